// Round 13
// baseline (109.572 us; speedup 1.0000x reference)
//
#include <hip/hip_runtime.h>
#include <cstdint>
#include <cstddef>

#define TB 2
#define TT 2048
#define TC 1024
#define TH 16
#define TD 64
#define MROWS (TB*TT)   // 4096

typedef __attribute__((ext_vector_type(8))) short bf16x8;
typedef __attribute__((ext_vector_type(4))) float f32x4;

// log2-domain softmax constants (f32, inside attn):
//   p = (s + mask) * 0.125 * log2(e);  exp(scores) == exp2(p)
#define QSCL2 0.18033688011112042f        // 0.125 * log2(e)
#define MASKL2 (-1.8033688e8f)            // -1e9 * 0.125 * log2(e)

__device__ __forceinline__ unsigned short f2bf(float f) {
  union { float f; unsigned int u; } x; x.f = f;
  unsigned int r = x.u + 0x7fffu + ((x.u >> 16) & 1u);
  return (unsigned short)(r >> 16);
}

__device__ __forceinline__ void gload16(const void* g, void* l) {
  __builtin_amdgcn_global_load_lds((const __attribute__((address_space(1))) void*)g,
                                   (__attribute__((address_space(3))) void*)l, 16, 0, 0);
}

#define WAITVM(N) do { asm volatile("s_waitcnt vmcnt(" #N ")" ::: "memory"); \
                       __builtin_amdgcn_sched_barrier(0); } while (0)

__device__ __forceinline__ float exp2h(float x) {   // hardware 2^x (trans pipe)
  float r;
  asm("v_exp_f32 %0, %1" : "=v"(r) : "v"(x));
  return r;
}

// ---------- merged prep: z<4 -> weight transpose; z>=4 -> f32->bf16 cast ----------
__global__ __launch_bounds__(256) void prep_kernel(
    const float* __restrict__ W0, const float* __restrict__ W1,
    const float* __restrict__ W2, const float* __restrict__ W3,
    unsigned short* __restrict__ T0, unsigned short* __restrict__ T1,
    unsigned short* __restrict__ T2, unsigned short* __restrict__ T3,
    const float* __restrict__ Q, const float* __restrict__ K, const float* __restrict__ V,
    unsigned short* __restrict__ qc, unsigned short* __restrict__ kc,
    unsigned short* __restrict__ vc) {
  const int z = blockIdx.z;
  if (z < 4) {
    const float* W = z == 0 ? W0 : (z == 1 ? W1 : (z == 2 ? W2 : W3));
    unsigned short* WT = z == 0 ? T0 : (z == 1 ? T1 : (z == 2 ? T2 : T3));
    __shared__ float ts[32][33];
    int tx = threadIdx.x & 31, ty = threadIdx.x >> 5;
    int n0 = blockIdx.x * 32, k0 = blockIdx.y * 32;
#pragma unroll
    for (int r = 0; r < 32; r += 8)
      ts[ty + r][tx] = W[(size_t)(k0 + ty + r) * TC + n0 + tx];
    __syncthreads();
#pragma unroll
    for (int r = 0; r < 32; r += 8)
      WT[(size_t)(n0 + ty + r) * TC + k0 + tx] = f2bf(ts[tx][ty + r]);
  } else {
    const int zt = z - 4;
    const float* in = zt == 0 ? Q : (zt == 1 ? K : V);
    unsigned short* out = zt == 0 ? qc : (zt == 1 ? kc : vc);
    const int lb = blockIdx.y * 32 + blockIdx.x;   // 0..1023, 4096 elems each
#pragma unroll
    for (int c = 0; c < 2; ++c) {
      int i = lb * 4096 + c * 2048 + threadIdx.x * 8;
      float4 f0 = *(const float4*)(in + i);
      float4 f1 = *(const float4*)(in + i + 4);
      union { unsigned short u[8]; int4 v; } pk;
      pk.u[0] = f2bf(f0.x); pk.u[1] = f2bf(f0.y); pk.u[2] = f2bf(f0.z); pk.u[3] = f2bf(f0.w);
      pk.u[4] = f2bf(f1.x); pk.u[5] = f2bf(f1.y); pk.u[6] = f2bf(f1.z); pk.u[7] = f2bf(f1.w);
      *(int4*)(out + i) = pk.v;
    }
  }
}

// ---------- standalone wtrans/cast (non-fat fallback path) ----------
__global__ __launch_bounds__(256) void wtrans4_kernel(
    const float* __restrict__ W0, const float* __restrict__ W1,
    const float* __restrict__ W2, const float* __restrict__ W3,
    unsigned short* __restrict__ T0, unsigned short* __restrict__ T1,
    unsigned short* __restrict__ T2, unsigned short* __restrict__ T3) {
  const int z = blockIdx.z;
  const float* W = z == 0 ? W0 : (z == 1 ? W1 : (z == 2 ? W2 : W3));
  unsigned short* WT = z == 0 ? T0 : (z == 1 ? T1 : (z == 2 ? T2 : T3));
  __shared__ float ts[32][33];
  int tx = threadIdx.x & 31, ty = threadIdx.x >> 5;
  int n0 = blockIdx.x * 32, k0 = blockIdx.y * 32;
#pragma unroll
  for (int r = 0; r < 32; r += 8)
    ts[ty + r][tx] = W[(size_t)(k0 + ty + r) * TC + n0 + tx];
  __syncthreads();
#pragma unroll
  for (int r = 0; r < 32; r += 8)
    WT[(size_t)(n0 + ty + r) * TC + k0 + tx] = f2bf(ts[tx][ty + r]);
}

__global__ __launch_bounds__(256) void cast3_kernel(
    const float* __restrict__ A, const float* __restrict__ B, const float* __restrict__ C,
    unsigned short* __restrict__ oa, unsigned short* __restrict__ ob,
    unsigned short* __restrict__ oc) {
  const int z = blockIdx.y;
  const float* in = z == 0 ? A : (z == 1 ? B : C);
  unsigned short* out = z == 0 ? oa : (z == 1 ? ob : oc);
  int i = (blockIdx.x * 256 + threadIdx.x) * 8;
  float4 f0 = *(const float4*)(in + i);
  float4 f1 = *(const float4*)(in + i + 4);
  union { unsigned short u[8]; int4 v; } pk;
  pk.u[0] = f2bf(f0.x); pk.u[1] = f2bf(f0.y); pk.u[2] = f2bf(f0.z); pk.u[3] = f2bf(f0.w);
  pk.u[4] = f2bf(f1.x); pk.u[5] = f2bf(f1.y); pk.u[6] = f2bf(f1.z); pk.u[7] = f2bf(f1.w);
  *(int4*)(out + i) = pk.v;
}

// ---------- fused QKV projection GEMM: 128x64 tile, 6 blocks/CU ----------
__global__ __launch_bounds__(256, 6)
void qkv_gemm_kernel(const unsigned short* __restrict__ Aq, const unsigned short* __restrict__ Ak,
                     const unsigned short* __restrict__ Av,
                     const unsigned short* __restrict__ BTq, const unsigned short* __restrict__ BTk,
                     const unsigned short* __restrict__ BTv,
                     const float* __restrict__ bq, const float* __restrict__ bk,
                     const float* __restrict__ bv,
                     unsigned short* __restrict__ Oq, unsigned short* __restrict__ Ok,
                     unsigned short* __restrict__ Ov, int zbase) {
  __shared__ __attribute__((aligned(16))) unsigned short As[128][64];
  __shared__ __attribute__((aligned(16))) unsigned short Bs[64][64];
  const int z = blockIdx.z + zbase;
  const unsigned short* A  = z == 0 ? Aq  : (z == 1 ? Ak  : Av);
  const unsigned short* Bt = z == 0 ? BTq : (z == 1 ? BTk : BTv);
  const float* bias        = z == 0 ? bq  : (z == 1 ? bk  : bv);
  unsigned short* Out      = z == 0 ? Oq  : (z == 1 ? Ok  : Ov);

  const int lin = blockIdx.y * 16 + blockIdx.x;       // 0..511
  const int swz = (lin & 7) * 64 + (lin >> 3);
  const int m0 = (swz >> 4) * 128, n0 = (swz & 15) * 64;

  const int tid = threadIdx.x, wave = tid >> 6, lane = tid & 63;
  const int lh = lane & 15, lq = lane >> 4;
  const int wr = wave >> 1, wc = wave & 1;
  const int srow = lane >> 3, sseg = (lane & 7) ^ srow;
  const f32x4 vzero = {0.f, 0.f, 0.f, 0.f};
  f32x4 acc[4][2];
#pragma unroll
  for (int i = 0; i < 4; ++i)
#pragma unroll
    for (int j = 0; j < 2; ++j) acc[i][j] = vzero;

  for (int k0 = 0; k0 < TC; k0 += 64) {
    __syncthreads();
#pragma unroll
    for (int c = 0; c < 4; ++c) {
      const int chunk = wave * 4 + c;
      const int row = chunk * 8 + srow;
      gload16(A + (size_t)(m0 + row) * TC + k0 + sseg * 8, &As[chunk * 8][0]);
    }
#pragma unroll
    for (int c = 0; c < 2; ++c) {
      const int chunk = wave * 2 + c;
      const int row = chunk * 8 + srow;
      gload16(Bt + (size_t)(n0 + row) * TC + k0 + sseg * 8, &Bs[chunk * 8][0]);
    }
    __syncthreads();
#pragma unroll
    for (int kk = 0; kk < 2; ++kk) {
      const int seg = kk * 4 + lq;
      bf16x8 a[4], b[2];
#pragma unroll
      for (int i = 0; i < 4; ++i) {
        int row = wr * 64 + i * 16 + lh;
        a[i] = *(const bf16x8*)&As[row][(seg ^ (row & 7)) << 3];
      }
#pragma unroll
      for (int j = 0; j < 2; ++j) {
        int row = wc * 32 + j * 16 + lh;
        b[j] = *(const bf16x8*)&Bs[row][(seg ^ (row & 7)) << 3];
      }
#pragma unroll
      for (int i = 0; i < 4; ++i)
#pragma unroll
        for (int j = 0; j < 2; ++j)
          acc[i][j] = __builtin_amdgcn_mfma_f32_16x16x32_bf16(a[i], b[j], acc[i][j], 0, 0, 0);
    }
  }

#pragma unroll
  for (int i = 0; i < 4; ++i)
#pragma unroll
    for (int j = 0; j < 2; ++j) {
      const int cg = n0 + wc * 32 + j * 16 + lh;
      const float bb = bias[cg];
      if (z == 2) {  // vT layout (b,h,d,t), pack 4 t's
        int rg0 = m0 + wr * 64 + i * 16 + lq * 4;
        int bidx = rg0 >> 11, t0 = rg0 & (TT - 1);
        int h = cg >> 6, d = cg & 63;
        unsigned long long pk = 0ull;
#pragma unroll
        for (int r = 0; r < 4; ++r)
          pk |= (unsigned long long)f2bf(acc[i][j][r] + bb) << (16 * r);
        *(unsigned long long*)(Out + ((size_t)((bidx * TH + h) * TD + d)) * TT + t0) = pk;
      } else {       // (b,h,t,d)
#pragma unroll
        for (int r = 0; r < 4; ++r) {
          int rg = m0 + wr * 64 + i * 16 + lq * 4 + r;
          int bidx = rg >> 11, t = rg & (TT - 1);
          int h = cg >> 6, d = cg & 63;
          Out[((size_t)((bidx * TH + h) * TT + t)) * TD + d] = f2bf(acc[i][j][r] + bb);
        }
      }
    }
}

// ---------- output projection GEMM: 64x64 tile, 4 blocks/CU, f32 out ----------
__global__ __launch_bounds__(256, 4)
void oproj_gemm_kernel(const unsigned short* __restrict__ A, const unsigned short* __restrict__ Bt,
                       const float* __restrict__ bias, float* __restrict__ Out) {
  __shared__ __attribute__((aligned(16))) unsigned short As[64][64];
  __shared__ __attribute__((aligned(16))) unsigned short Bs[64][64];
  const int lin = blockIdx.y * 16 + blockIdx.x;       // 0..1023
  const int swz = (lin & 7) * 128 + (lin >> 3);
  const int m0 = (swz >> 4) * 64, n0 = (swz & 15) * 64;

  const int tid = threadIdx.x, wave = tid >> 6, lane = tid & 63;
  const int lh = lane & 15, lq = lane >> 4;
  const int wr = wave >> 1, wc = wave & 1;
  const int srow = lane >> 3, sseg = (lane & 7) ^ srow;
  const f32x4 vzero = {0.f, 0.f, 0.f, 0.f};
  f32x4 acc[2][2];
#pragma unroll
  for (int i = 0; i < 2; ++i)
#pragma unroll
    for (int j = 0; j < 2; ++j) acc[i][j] = vzero;

  for (int k0 = 0; k0 < TC; k0 += 64) {
    __syncthreads();
#pragma unroll
    for (int c = 0; c < 2; ++c) {
      const int chunk = wave * 2 + c;
      const int row = chunk * 8 + srow;
      gload16(A + (size_t)(m0 + row) * TC + k0 + sseg * 8, &As[chunk * 8][0]);
      gload16(Bt + (size_t)(n0 + row) * TC + k0 + sseg * 8, &Bs[chunk * 8][0]);
    }
    __syncthreads();
#pragma unroll
    for (int kk = 0; kk < 2; ++kk) {
      const int seg = kk * 4 + lq;
      bf16x8 a[2], b[2];
#pragma unroll
      for (int i = 0; i < 2; ++i) {
        int row = wr * 32 + i * 16 + lh;
        a[i] = *(const bf16x8*)&As[row][(seg ^ (row & 7)) << 3];
      }
#pragma unroll
      for (int j = 0; j < 2; ++j) {
        int row = wc * 32 + j * 16 + lh;
        b[j] = *(const bf16x8*)&Bs[row][(seg ^ (row & 7)) << 3];
      }
#pragma unroll
      for (int i = 0; i < 2; ++i)
#pragma unroll
        for (int j = 0; j < 2; ++j)
          acc[i][j] = __builtin_amdgcn_mfma_f32_16x16x32_bf16(a[i], b[j], acc[i][j], 0, 0, 0);
    }
  }

#pragma unroll
  for (int i = 0; i < 2; ++i)
#pragma unroll
    for (int j = 0; j < 2; ++j) {
      const int cg = n0 + wc * 32 + j * 16 + lh;
      const float bb = bias[cg];
#pragma unroll
      for (int r = 0; r < 4; ++r) {
        int rg = m0 + wr * 32 + i * 16 + lq * 4 + r;
        Out[(size_t)rg * TC + cg] = acc[i][j][r] + bb;
      }
    }
}

// ---------- causal flash attention: QBLK=128, 8 waves, shared K/V staging ----------
// 512 blocks x 512 threads (2 blocks/CU x 8 waves = 16 waves/CU). Each wave owns
// 16 q rows; K/V staged once per 128 q rows (half the traffic/barriers of QBLK=64).
// Fully-masked wave-tiles are skipped (their P underflows to exactly 0 anyway).
// q,k: (bh,t,d) bf16 ; vT: (bh,d,t) bf16 ; out: (b,t,h*64+d) bf16
__global__ __launch_bounds__(512, 4)
void attn_kernel(const unsigned short* __restrict__ qb, const unsigned short* __restrict__ kb,
                 const unsigned short* __restrict__ vtb, unsigned short* __restrict__ ob) {
  __shared__ __attribute__((aligned(16))) unsigned short Qs[128][64];
  __shared__ __attribute__((aligned(16))) unsigned short Ks[2][64][64];
  __shared__ __attribute__((aligned(16))) unsigned short Vs[2][64][64];
  const int tid = threadIdx.x, wave = tid >> 6, lane = tid & 63;
  const int lh = lane & 15, lq = lane >> 4;
  const int srow = lane >> 3, sseg = (lane & 7) ^ srow;
  const int swzA = lh & 7;

  // id bits: [2:0]=XCD (4 heads each), [4:3]=head-in-XCD, [8:5]=q-tile (descending)
  const int id = blockIdx.x;             // 512 blocks
  const int bh = (id & 7) * 4 + ((id >> 3) & 3);
  const int bx = 15 - (id >> 5);         // LPT: longest causal blocks first
  const size_t qkb = (size_t)bh * TT * TD;
  const size_t vob = (size_t)bh * TD * TT;
  const int bidx = bh >> 4, h = bh & 15;
  const f32x4 vzero = {0.f, 0.f, 0.f, 0.f};

  union { unsigned short u[8]; bf16x8 v; } onef;
#pragma unroll
  for (int i = 0; i < 8; ++i) onef.u[i] = 0x3F80;   // bf16 1.0

  // stageKV: 2 gload16/thread (1 K row-chunk + 1 V row-chunk); wave w stages rows 8w..8w+7
  auto stageKV = [&](int buf, int t) {
    const int kv0 = t * 64;
    const int row = wave * 8 + srow;
    gload16(kb + qkb + (size_t)(kv0 + row) * TD + sseg * 8, &Ks[buf][wave * 8][0]);
    gload16(vtb + vob + (size_t)row * TT + kv0 + sseg * 8, &Vs[buf][wave * 8][0]);
  };

  const int q0 = bx * 128;
  const int nt = 2 * (bx + 1);           // nt >= 2 always
  const int qlo = q0 + wave * 16;        // this wave's q-row range [qlo, qlo+15]
  const int q_g = qlo + lh;

  // prologue: Q (wave stages exactly its own 16 rows: chunks 2w, 2w+1) + tiles 0,1
#pragma unroll
  for (int c = 0; c < 2; ++c) {
    const int chunk = wave * 2 + c;
    const int row = chunk * 8 + srow;
    gload16(qb + qkb + (size_t)(q0 + row) * TD + sseg * 8, &Qs[chunk * 8][0]);
  }
  stageKV(0, 0);
  stageKV(1, 1);
  WAITVM(2);                             // Q + tile0 done; tile1 in flight
  bf16x8 aq[2];
  {
    const int row = wave * 16 + lh;
#pragma unroll
    for (int kk = 0; kk < 2; ++kk)
      aq[kk] = *(const bf16x8*)&Qs[row][((kk * 4 + lq) ^ (row & 7)) << 3];
  }
  f32x4 oacc[4], lacc = vzero;
#pragma unroll
  for (int jt = 0; jt < 4; ++jt) oacc[jt] = vzero;

  for (int t = 0; t < nt; ++t) {
    const int cur = t & 1;
    const int kv0 = t * 64;
    if (t >= 1 && t + 1 < nt) stageKV(cur ^ 1, t + 1);
    if (t + 1 < nt) { WAITVM(2); } else { WAITVM(0); }
    __builtin_amdgcn_s_barrier();

    if (kv0 <= qlo + 15) {               // skip fully-masked wave-tiles (P == 0)
      f32x4 accS[4];
#pragma unroll
      for (int j = 0; j < 4; ++j) accS[j] = vzero;
      __builtin_amdgcn_s_setprio(1);
#pragma unroll
      for (int kk = 0; kk < 2; ++kk) {
#pragma unroll
        for (int j = 0; j < 4; ++j) {
          bf16x8 bk = *(const bf16x8*)&Ks[cur][j * 16 + lh][((kk * 4 + lq) ^ swzA) << 3];
          accS[j] = __builtin_amdgcn_mfma_f32_16x16x32_bf16(bk, aq[kk], accS[j], 0, 0, 0);
        }
      }
      __builtin_amdgcn_s_setprio(0);

      float p_[16];
      if (kv0 + 63 > qlo) {              // tile overlaps this wave's diagonal
#pragma unroll
        for (int j = 0; j < 4; ++j)
#pragma unroll
          for (int r = 0; r < 4; ++r) {
            const int kvg = kv0 + j * 16 + lq * 4 + r;
            p_[j * 4 + r] = fmaf(accS[j][r], QSCL2, (kvg <= q_g) ? 0.f : MASKL2);
          }
      } else {
#pragma unroll
        for (int j = 0; j < 4; ++j)
#pragma unroll
          for (int r = 0; r < 4; ++r)
            p_[j * 4 + r] = accS[j][r] * QSCL2;
      }
#pragma unroll
      for (int i = 0; i < 16; ++i) p_[i] = exp2h(p_[i]);

      unsigned Dw[8];  // [j][tt]
#pragma unroll
      for (int j = 0; j < 4; ++j)
#pragma unroll
        for (int tt = 0; tt < 2; ++tt)
          asm("v_cvt_pk_bf16_f32 %0, %1, %2"
              : "=v"(Dw[j * 2 + tt]) : "v"(p_[j * 4 + 2 * tt]), "v"(p_[j * 4 + 2 * tt + 1]));
#pragma unroll
      for (int ks = 0; ks < 2; ++ks) {
        unsigned x0 = Dw[(2 * ks) * 2 + 0], y0 = Dw[(2 * ks + 1) * 2 + 0];
        unsigned x1 = Dw[(2 * ks) * 2 + 1], y1 = Dw[(2 * ks + 1) * 2 + 1];
        asm("v_permlane32_swap_b32 %0, %1" : "+v"(x0), "+v"(y0));
        asm("v_permlane16_swap_b32 %0, %1" : "+v"(x0), "+v"(y0));
        asm("v_permlane32_swap_b32 %0, %1" : "+v"(x1), "+v"(y1));
        asm("v_permlane16_swap_b32 %0, %1" : "+v"(x1), "+v"(y1));
        union { unsigned u[4]; bf16x8 v; } pb;
        pb.u[0] = x0; pb.u[1] = x1; pb.u[2] = y0; pb.u[3] = y1;
        __builtin_amdgcn_s_setprio(1);
#pragma unroll
        for (int jt = 0; jt < 4; ++jt) {
          bf16x8 av = *(const bf16x8*)&Vs[cur][jt * 16 + lh][((ks * 4 + lq) ^ swzA) << 3];
          oacc[jt] = __builtin_amdgcn_mfma_f32_16x16x32_bf16(av, pb.v, oacc[jt], 0, 0, 0);
        }
        lacc = __builtin_amdgcn_mfma_f32_16x16x32_bf16(onef.v, pb.v, lacc, 0, 0, 0);
        __builtin_amdgcn_s_setprio(0);
      }
    }
    __builtin_amdgcn_s_barrier();
  }

  const float inv = 1.f / lacc[0];
  unsigned short* orow = ob + ((size_t)(bidx * TT + q_g)) * TC + h * TD;
#pragma unroll
  for (int jt = 0; jt < 4; ++jt) {
    unsigned long long pk = 0ull;
#pragma unroll
    for (int r = 0; r < 4; ++r)
      pk |= (unsigned long long)f2bf(oacc[jt][r] * inv) << (16 * r);
    *(unsigned long long*)(orow + jt * 16 + lq * 4) = pk;
  }
}

extern "C" void kernel_launch(void* const* d_in, const int* in_sizes, int n_in,
                              void* d_out, int out_size, void* d_ws, size_t ws_size,
                              hipStream_t stream) {
  const float* Q  = (const float*)d_in[0];
  const float* K  = (const float*)d_in[1];
  const float* V  = (const float*)d_in[2];
  const float* Wq = (const float*)d_in[3];
  const float* bq = (const float*)d_in[4];
  const float* Wk = (const float*)d_in[5];
  const float* bk = (const float*)d_in[6];
  const float* Wv = (const float*)d_in[7];
  const float* bv = (const float*)d_in[8];
  const float* Wo = (const float*)d_in[9];
  const float* bo = (const float*)d_in[10];
  float* out = (float*)d_out;

  char* ws = (char*)d_ws;
  const size_t MB = 1ull << 20;
  unsigned short* WqT = (unsigned short*)(ws + 0 * MB);
  unsigned short* WkT = (unsigned short*)(ws + 2 * MB);
  unsigned short* WvT = (unsigned short*)(ws + 4 * MB);
  unsigned short* WoT = (unsigned short*)(ws + 6 * MB);

  const bool fat = ws_size >= 56 * MB;
  unsigned short *qc, *kc, *vc, *qbuf, *kbuf, *vtbuf, *aout;
  if (fat) {
    qc    = (unsigned short*)(ws + 8 * MB);
    kc    = (unsigned short*)(ws + 16 * MB);
    vc    = (unsigned short*)(ws + 24 * MB);
    qbuf  = (unsigned short*)(ws + 32 * MB);
    kbuf  = (unsigned short*)(ws + 40 * MB);
    vtbuf = (unsigned short*)(ws + 48 * MB);
    aout  = qc;  // qc dead after qkv gemm
  } else {
    qc = kc = vc = (unsigned short*)(ws + 8 * MB);
    qbuf  = (unsigned short*)(ws + 16 * MB);
    kbuf  = (unsigned short*)(ws + 24 * MB);
    vtbuf = (unsigned short*)(ws + 32 * MB);
    aout  = qc;
  }

  dim3 blk(256);
  if (fat) {
    prep_kernel<<<dim3(32, 32, 7), blk, 0, stream>>>(
        Wq, Wk, Wv, Wo, WqT, WkT, WvT, WoT, Q, K, V, qc, kc, vc);
    qkv_gemm_kernel<<<dim3(16, 32, 3), blk, 0, stream>>>(
        qc, kc, vc, WqT, WkT, WvT, bq, bk, bv, qbuf, kbuf, vtbuf, 0);
  } else {
    const int castGrid = MROWS * TC / (256 * 8);  // 2048
    wtrans4_kernel<<<dim3(32, 32, 4), blk, 0, stream>>>(Wq, Wk, Wv, Wo, WqT, WkT, WvT, WoT);
    cast3_kernel<<<dim3(castGrid, 1), blk, 0, stream>>>(Q, Q, Q, qc, qc, qc);
    qkv_gemm_kernel<<<dim3(16, 32, 1), blk, 0, stream>>>(
        qc, qc, qc, WqT, WkT, WvT, bq, bk, bv, qbuf, kbuf, vtbuf, 0);
    cast3_kernel<<<dim3(castGrid, 1), blk, 0, stream>>>(K, K, K, kc, kc, kc);
    qkv_gemm_kernel<<<dim3(16, 32, 1), blk, 0, stream>>>(
        kc, kc, kc, WqT, WkT, WvT, bq, bk, bv, qbuf, kbuf, vtbuf, 1);
    cast3_kernel<<<dim3(castGrid, 1), blk, 0, stream>>>(V, V, V, vc, vc, vc);
    qkv_gemm_kernel<<<dim3(16, 32, 1), blk, 0, stream>>>(
        vc, vc, vc, WqT, WkT, WvT, bq, bk, bv, qbuf, kbuf, vtbuf, 2);
  }

  attn_kernel<<<dim3(512), dim3(512), 0, stream>>>(qbuf, kbuf, vtbuf, aout);

  oproj_gemm_kernel<<<dim3(16, 64), blk, 0, stream>>>(aout, WoT, bo, out);
}

// Round 14
// 102.820 us; speedup vs baseline: 1.0657x; 1.0657x over previous
//
#include <hip/hip_runtime.h>
#include <cstdint>
#include <cstddef>

#define TB 2
#define TT 2048
#define TC 1024
#define TH 16
#define TD 64
#define MROWS (TB*TT)   // 4096

typedef __attribute__((ext_vector_type(8))) short bf16x8;
typedef __attribute__((ext_vector_type(4))) float f32x4;

// log2-domain softmax constants (f32, inside attn):
//   p = (s + mask) * 0.125 * log2(e);  exp(scores) == exp2(p)
#define QSCL2 0.18033688011112042f        // 0.125 * log2(e)
#define MASKL2 (-1.8033688e8f)            // -1e9 * 0.125 * log2(e)

__device__ __forceinline__ unsigned short f2bf(float f) {
  union { float f; unsigned int u; } x; x.f = f;
  unsigned int r = x.u + 0x7fffu + ((x.u >> 16) & 1u);
  return (unsigned short)(r >> 16);
}

__device__ __forceinline__ void gload16(const void* g, void* l) {
  __builtin_amdgcn_global_load_lds((const __attribute__((address_space(1))) void*)g,
                                   (__attribute__((address_space(3))) void*)l, 16, 0, 0);
}

#define WAITVM(N) do { asm volatile("s_waitcnt vmcnt(" #N ")" ::: "memory"); \
                       __builtin_amdgcn_sched_barrier(0); } while (0)

__device__ __forceinline__ float exp2h(float x) {   // hardware 2^x (trans pipe)
  float r;
  asm("v_exp_f32 %0, %1" : "=v"(r) : "v"(x));
  return r;
}

// ---------- merged prep: z<4 -> weight transpose; z>=4 -> f32->bf16 cast ----------
__global__ __launch_bounds__(256) void prep_kernel(
    const float* __restrict__ W0, const float* __restrict__ W1,
    const float* __restrict__ W2, const float* __restrict__ W3,
    unsigned short* __restrict__ T0, unsigned short* __restrict__ T1,
    unsigned short* __restrict__ T2, unsigned short* __restrict__ T3,
    const float* __restrict__ Q, const float* __restrict__ K, const float* __restrict__ V,
    unsigned short* __restrict__ qc, unsigned short* __restrict__ kc,
    unsigned short* __restrict__ vc) {
  const int z = blockIdx.z;
  if (z < 4) {
    const float* W = z == 0 ? W0 : (z == 1 ? W1 : (z == 2 ? W2 : W3));
    unsigned short* WT = z == 0 ? T0 : (z == 1 ? T1 : (z == 2 ? T2 : T3));
    __shared__ float ts[32][33];
    int tx = threadIdx.x & 31, ty = threadIdx.x >> 5;
    int n0 = blockIdx.x * 32, k0 = blockIdx.y * 32;
#pragma unroll
    for (int r = 0; r < 32; r += 8)
      ts[ty + r][tx] = W[(size_t)(k0 + ty + r) * TC + n0 + tx];
    __syncthreads();
#pragma unroll
    for (int r = 0; r < 32; r += 8)
      WT[(size_t)(n0 + ty + r) * TC + k0 + tx] = f2bf(ts[tx][ty + r]);
  } else {
    const int zt = z - 4;
    const float* in = zt == 0 ? Q : (zt == 1 ? K : V);
    unsigned short* out = zt == 0 ? qc : (zt == 1 ? kc : vc);
    const int lb = blockIdx.y * 32 + blockIdx.x;   // 0..1023, 4096 elems each
#pragma unroll
    for (int c = 0; c < 2; ++c) {
      int i = lb * 4096 + c * 2048 + threadIdx.x * 8;
      float4 f0 = *(const float4*)(in + i);
      float4 f1 = *(const float4*)(in + i + 4);
      union { unsigned short u[8]; int4 v; } pk;
      pk.u[0] = f2bf(f0.x); pk.u[1] = f2bf(f0.y); pk.u[2] = f2bf(f0.z); pk.u[3] = f2bf(f0.w);
      pk.u[4] = f2bf(f1.x); pk.u[5] = f2bf(f1.y); pk.u[6] = f2bf(f1.z); pk.u[7] = f2bf(f1.w);
      *(int4*)(out + i) = pk.v;
    }
  }
}

// ---------- standalone wtrans/cast (non-fat fallback path) ----------
__global__ __launch_bounds__(256) void wtrans4_kernel(
    const float* __restrict__ W0, const float* __restrict__ W1,
    const float* __restrict__ W2, const float* __restrict__ W3,
    unsigned short* __restrict__ T0, unsigned short* __restrict__ T1,
    unsigned short* __restrict__ T2, unsigned short* __restrict__ T3) {
  const int z = blockIdx.z;
  const float* W = z == 0 ? W0 : (z == 1 ? W1 : (z == 2 ? W2 : W3));
  unsigned short* WT = z == 0 ? T0 : (z == 1 ? T1 : (z == 2 ? T2 : T3));
  __shared__ float ts[32][33];
  int tx = threadIdx.x & 31, ty = threadIdx.x >> 5;
  int n0 = blockIdx.x * 32, k0 = blockIdx.y * 32;
#pragma unroll
  for (int r = 0; r < 32; r += 8)
    ts[ty + r][tx] = W[(size_t)(k0 + ty + r) * TC + n0 + tx];
  __syncthreads();
#pragma unroll
  for (int r = 0; r < 32; r += 8)
    WT[(size_t)(n0 + ty + r) * TC + k0 + tx] = f2bf(ts[tx][ty + r]);
}

__global__ __launch_bounds__(256) void cast3_kernel(
    const float* __restrict__ A, const float* __restrict__ B, const float* __restrict__ C,
    unsigned short* __restrict__ oa, unsigned short* __restrict__ ob,
    unsigned short* __restrict__ oc) {
  const int z = blockIdx.y;
  const float* in = z == 0 ? A : (z == 1 ? B : C);
  unsigned short* out = z == 0 ? oa : (z == 1 ? ob : oc);
  int i = (blockIdx.x * 256 + threadIdx.x) * 8;
  float4 f0 = *(const float4*)(in + i);
  float4 f1 = *(const float4*)(in + i + 4);
  union { unsigned short u[8]; int4 v; } pk;
  pk.u[0] = f2bf(f0.x); pk.u[1] = f2bf(f0.y); pk.u[2] = f2bf(f0.z); pk.u[3] = f2bf(f0.w);
  pk.u[4] = f2bf(f1.x); pk.u[5] = f2bf(f1.y); pk.u[6] = f2bf(f1.z); pk.u[7] = f2bf(f1.w);
  *(int4*)(out + i) = pk.v;
}

// ---------- fused QKV projection GEMM: 128x64 tile, 6 blocks/CU ----------
__global__ __launch_bounds__(256, 6)
void qkv_gemm_kernel(const unsigned short* __restrict__ Aq, const unsigned short* __restrict__ Ak,
                     const unsigned short* __restrict__ Av,
                     const unsigned short* __restrict__ BTq, const unsigned short* __restrict__ BTk,
                     const unsigned short* __restrict__ BTv,
                     const float* __restrict__ bq, const float* __restrict__ bk,
                     const float* __restrict__ bv,
                     unsigned short* __restrict__ Oq, unsigned short* __restrict__ Ok,
                     unsigned short* __restrict__ Ov, int zbase) {
  __shared__ __attribute__((aligned(16))) unsigned short As[128][64];
  __shared__ __attribute__((aligned(16))) unsigned short Bs[64][64];
  const int z = blockIdx.z + zbase;
  const unsigned short* A  = z == 0 ? Aq  : (z == 1 ? Ak  : Av);
  const unsigned short* Bt = z == 0 ? BTq : (z == 1 ? BTk : BTv);
  const float* bias        = z == 0 ? bq  : (z == 1 ? bk  : bv);
  unsigned short* Out      = z == 0 ? Oq  : (z == 1 ? Ok  : Ov);

  const int lin = blockIdx.y * 16 + blockIdx.x;       // 0..511
  const int swz = (lin & 7) * 64 + (lin >> 3);
  const int m0 = (swz >> 4) * 128, n0 = (swz & 15) * 64;

  const int tid = threadIdx.x, wave = tid >> 6, lane = tid & 63;
  const int lh = lane & 15, lq = lane >> 4;
  const int wr = wave >> 1, wc = wave & 1;
  const int srow = lane >> 3, sseg = (lane & 7) ^ srow;
  const f32x4 vzero = {0.f, 0.f, 0.f, 0.f};
  f32x4 acc[4][2];
#pragma unroll
  for (int i = 0; i < 4; ++i)
#pragma unroll
    for (int j = 0; j < 2; ++j) acc[i][j] = vzero;

  for (int k0 = 0; k0 < TC; k0 += 64) {
    __syncthreads();
#pragma unroll
    for (int c = 0; c < 4; ++c) {
      const int chunk = wave * 4 + c;
      const int row = chunk * 8 + srow;
      gload16(A + (size_t)(m0 + row) * TC + k0 + sseg * 8, &As[chunk * 8][0]);
    }
#pragma unroll
    for (int c = 0; c < 2; ++c) {
      const int chunk = wave * 2 + c;
      const int row = chunk * 8 + srow;
      gload16(Bt + (size_t)(n0 + row) * TC + k0 + sseg * 8, &Bs[chunk * 8][0]);
    }
    __syncthreads();
#pragma unroll
    for (int kk = 0; kk < 2; ++kk) {
      const int seg = kk * 4 + lq;
      bf16x8 a[4], b[2];
#pragma unroll
      for (int i = 0; i < 4; ++i) {
        int row = wr * 64 + i * 16 + lh;
        a[i] = *(const bf16x8*)&As[row][(seg ^ (row & 7)) << 3];
      }
#pragma unroll
      for (int j = 0; j < 2; ++j) {
        int row = wc * 32 + j * 16 + lh;
        b[j] = *(const bf16x8*)&Bs[row][(seg ^ (row & 7)) << 3];
      }
#pragma unroll
      for (int i = 0; i < 4; ++i)
#pragma unroll
        for (int j = 0; j < 2; ++j)
          acc[i][j] = __builtin_amdgcn_mfma_f32_16x16x32_bf16(a[i], b[j], acc[i][j], 0, 0, 0);
    }
  }

#pragma unroll
  for (int i = 0; i < 4; ++i)
#pragma unroll
    for (int j = 0; j < 2; ++j) {
      const int cg = n0 + wc * 32 + j * 16 + lh;
      const float bb = bias[cg];
      if (z == 2) {  // vT layout (b,h,d,t), pack 4 t's
        int rg0 = m0 + wr * 64 + i * 16 + lq * 4;
        int bidx = rg0 >> 11, t0 = rg0 & (TT - 1);
        int h = cg >> 6, d = cg & 63;
        unsigned long long pk = 0ull;
#pragma unroll
        for (int r = 0; r < 4; ++r)
          pk |= (unsigned long long)f2bf(acc[i][j][r] + bb) << (16 * r);
        *(unsigned long long*)(Out + ((size_t)((bidx * TH + h) * TD + d)) * TT + t0) = pk;
      } else {       // (b,h,t,d)
#pragma unroll
        for (int r = 0; r < 4; ++r) {
          int rg = m0 + wr * 64 + i * 16 + lq * 4 + r;
          int bidx = rg >> 11, t = rg & (TT - 1);
          int h = cg >> 6, d = cg & 63;
          Out[((size_t)((bidx * TH + h) * TT + t)) * TD + d] = f2bf(acc[i][j][r] + bb);
        }
      }
    }
}

// ---------- output projection GEMM: 64x64 tile, 4 blocks/CU, f32 out ----------
__global__ __launch_bounds__(256, 4)
void oproj_gemm_kernel(const unsigned short* __restrict__ A, const unsigned short* __restrict__ Bt,
                       const float* __restrict__ bias, float* __restrict__ Out) {
  __shared__ __attribute__((aligned(16))) unsigned short As[64][64];
  __shared__ __attribute__((aligned(16))) unsigned short Bs[64][64];
  const int lin = blockIdx.y * 16 + blockIdx.x;       // 0..1023
  const int swz = (lin & 7) * 128 + (lin >> 3);
  const int m0 = (swz >> 4) * 64, n0 = (swz & 15) * 64;

  const int tid = threadIdx.x, wave = tid >> 6, lane = tid & 63;
  const int lh = lane & 15, lq = lane >> 4;
  const int wr = wave >> 1, wc = wave & 1;
  const int srow = lane >> 3, sseg = (lane & 7) ^ srow;
  const f32x4 vzero = {0.f, 0.f, 0.f, 0.f};
  f32x4 acc[2][2];
#pragma unroll
  for (int i = 0; i < 2; ++i)
#pragma unroll
    for (int j = 0; j < 2; ++j) acc[i][j] = vzero;

  for (int k0 = 0; k0 < TC; k0 += 64) {
    __syncthreads();
#pragma unroll
    for (int c = 0; c < 2; ++c) {
      const int chunk = wave * 2 + c;
      const int row = chunk * 8 + srow;
      gload16(A + (size_t)(m0 + row) * TC + k0 + sseg * 8, &As[chunk * 8][0]);
      gload16(Bt + (size_t)(n0 + row) * TC + k0 + sseg * 8, &Bs[chunk * 8][0]);
    }
    __syncthreads();
#pragma unroll
    for (int kk = 0; kk < 2; ++kk) {
      const int seg = kk * 4 + lq;
      bf16x8 a[2], b[2];
#pragma unroll
      for (int i = 0; i < 2; ++i) {
        int row = wr * 32 + i * 16 + lh;
        a[i] = *(const bf16x8*)&As[row][(seg ^ (row & 7)) << 3];
      }
#pragma unroll
      for (int j = 0; j < 2; ++j) {
        int row = wc * 32 + j * 16 + lh;
        b[j] = *(const bf16x8*)&Bs[row][(seg ^ (row & 7)) << 3];
      }
#pragma unroll
      for (int i = 0; i < 2; ++i)
#pragma unroll
        for (int j = 0; j < 2; ++j)
          acc[i][j] = __builtin_amdgcn_mfma_f32_16x16x32_bf16(a[i], b[j], acc[i][j], 0, 0, 0);
    }
  }

#pragma unroll
  for (int i = 0; i < 2; ++i)
#pragma unroll
    for (int j = 0; j < 2; ++j) {
      const int cg = n0 + wc * 32 + j * 16 + lh;
      const float bb = bias[cg];
#pragma unroll
      for (int r = 0; r < 4; ++r) {
        int rg = m0 + wr * 32 + i * 16 + lq * 4 + r;
        Out[(size_t)rg * TC + cg] = acc[i][j][r] + bb;
      }
    }
}

// ---------- causal flash attention: QBLK=64, 4 waves, ONE barrier per KV-tile ----
// Loop shape per tile: [WAITVM(0) own tile-t loads] -> barrier -> stage(t+1)
// -> compute(t). Consume-safety: every wave drains its own gload_lds before the
// barrier, so all waves' staged rows are LDS-visible after it. Overwrite-safety:
// stage(t+1) targets buf[(t+1)&1], last read in compute(t-1), which completed
// before this barrier. Prefetch still spans the full compute phase.
// q,k: (bh,t,d) bf16 ; vT: (bh,d,t) bf16 ; out: (b,t,h*64+d) bf16
__global__ __launch_bounds__(256, 4)
void attn_kernel(const unsigned short* __restrict__ qb, const unsigned short* __restrict__ kb,
                 const unsigned short* __restrict__ vtb, unsigned short* __restrict__ ob) {
  __shared__ __attribute__((aligned(16))) unsigned short Qs[64][64];
  __shared__ __attribute__((aligned(16))) unsigned short Ks[2][64][64];
  __shared__ __attribute__((aligned(16))) unsigned short Vs[2][64][64];
  const int tid = threadIdx.x, wave = tid >> 6, lane = tid & 63;
  const int lh = lane & 15, lq = lane >> 4;
  const int srow = lane >> 3, sseg = (lane & 7) ^ srow;
  const int swzA = lh & 7;

  // id bits: [2:0]=XCD (4 heads each), [4:3]=head-in-XCD, [9:5]=q-tile (descending)
  const int id = blockIdx.x;             // 1024 blocks
  const int bh = (id & 7) * 4 + ((id >> 3) & 3);
  const int bx = 31 - (id >> 5);         // LPT: longest causal blocks first
  const size_t qkb = (size_t)bh * TT * TD;
  const size_t vob = (size_t)bh * TD * TT;
  const int bidx = bh >> 4, h = bh & 15;
  const f32x4 vzero = {0.f, 0.f, 0.f, 0.f};

  union { unsigned short u[8]; bf16x8 v; } onef;
#pragma unroll
  for (int i = 0; i < 8; ++i) onef.u[i] = 0x3F80;   // bf16 1.0

  auto stageKV = [&](int buf, int t) {
    const int kv0 = t * 64;
#pragma unroll
    for (int c = 0; c < 2; ++c) {
      const int chunk = wave * 2 + c;
      const int row = chunk * 8 + srow;
      gload16(kb + qkb + (size_t)(kv0 + row) * TD + sseg * 8, &Ks[buf][chunk * 8][0]);
      gload16(vtb + vob + (size_t)row * TT + kv0 + sseg * 8, &Vs[buf][chunk * 8][0]);
    }
  };

  const int q0 = bx * 64;
  const int nt = bx + 1;
  const int q_g = q0 + wave * 16 + lh;

  // prologue: Q (this wave's rows) + tile0; drain, then read this wave's aq
#pragma unroll
  for (int c = 0; c < 2; ++c) {
    const int chunk = wave * 2 + c;
    const int row = chunk * 8 + srow;
    gload16(qb + qkb + (size_t)(q0 + row) * TD + sseg * 8, &Qs[chunk * 8][0]);
  }
  stageKV(0, 0);
  WAITVM(0);
  bf16x8 aq[2];
  {
    const int row = wave * 16 + lh;
#pragma unroll
    for (int kk = 0; kk < 2; ++kk)
      aq[kk] = *(const bf16x8*)&Qs[row][((kk * 4 + lq) ^ (row & 7)) << 3];
  }
  f32x4 oacc[4], lacc = vzero;
#pragma unroll
  for (int jt = 0; jt < 4; ++jt) oacc[jt] = vzero;

  for (int t = 0; t < nt; ++t) {
    const int cur = t & 1;
    const int kv0 = t * 64;
    __builtin_amdgcn_s_barrier();        // tile t visible from all waves
    if (t + 1 < nt) stageKV(cur ^ 1, t + 1);

    // QK^T swapped: accS[j] holds S^T[kv=16j+4lq+r][q=lh]
    f32x4 accS[4];
#pragma unroll
    for (int j = 0; j < 4; ++j) accS[j] = vzero;
    __builtin_amdgcn_s_setprio(1);
#pragma unroll
    for (int kk = 0; kk < 2; ++kk) {
#pragma unroll
      for (int j = 0; j < 4; ++j) {
        bf16x8 bk = *(const bf16x8*)&Ks[cur][j * 16 + lh][((kk * 4 + lq) ^ swzA) << 3];
        accS[j] = __builtin_amdgcn_mfma_f32_16x16x32_bf16(bk, aq[kk], accS[j], 0, 0, 0);
      }
    }
    __builtin_amdgcn_s_setprio(0);

    // fixed-max softmax: P = exp2((s+mask)*QSCL2). Mask ops only on diagonal.
    float p_[16];
    if (t == bx) {
#pragma unroll
      for (int j = 0; j < 4; ++j)
#pragma unroll
        for (int r = 0; r < 4; ++r) {
          const int kvg = kv0 + j * 16 + lq * 4 + r;
          p_[j * 4 + r] = fmaf(accS[j][r], QSCL2, (kvg <= q_g) ? 0.f : MASKL2);
        }
    } else {
#pragma unroll
      for (int j = 0; j < 4; ++j)
#pragma unroll
        for (int r = 0; r < 4; ++r)
          p_[j * 4 + r] = accS[j][r] * QSCL2;
    }
#pragma unroll
    for (int i = 0; i < 16; ++i) p_[i] = exp2h(p_[i]);

    // pack P -> bf16 dwords and build PV B-fragments in-register
    unsigned Dw[8];  // [j][tt]
#pragma unroll
    for (int j = 0; j < 4; ++j)
#pragma unroll
      for (int tt = 0; tt < 2; ++tt)
        asm("v_cvt_pk_bf16_f32 %0, %1, %2"
            : "=v"(Dw[j * 2 + tt]) : "v"(p_[j * 4 + 2 * tt]), "v"(p_[j * 4 + 2 * tt + 1]));
#pragma unroll
    for (int ks = 0; ks < 2; ++ks) {
      unsigned x0 = Dw[(2 * ks) * 2 + 0], y0 = Dw[(2 * ks + 1) * 2 + 0];
      unsigned x1 = Dw[(2 * ks) * 2 + 1], y1 = Dw[(2 * ks + 1) * 2 + 1];
      asm("v_permlane32_swap_b32 %0, %1" : "+v"(x0), "+v"(y0));
      asm("v_permlane16_swap_b32 %0, %1" : "+v"(x0), "+v"(y0));
      asm("v_permlane32_swap_b32 %0, %1" : "+v"(x1), "+v"(y1));
      asm("v_permlane16_swap_b32 %0, %1" : "+v"(x1), "+v"(y1));
      union { unsigned u[4]; bf16x8 v; } pb;
      pb.u[0] = x0; pb.u[1] = x1; pb.u[2] = y0; pb.u[3] = y1;
      __builtin_amdgcn_s_setprio(1);
#pragma unroll
      for (int jt = 0; jt < 4; ++jt) {
        bf16x8 av = *(const bf16x8*)&Vs[cur][jt * 16 + lh][((ks * 4 + lq) ^ swzA) << 3];
        oacc[jt] = __builtin_amdgcn_mfma_f32_16x16x32_bf16(av, pb.v, oacc[jt], 0, 0, 0);
      }
      lacc = __builtin_amdgcn_mfma_f32_16x16x32_bf16(onef.v, pb.v, lacc, 0, 0, 0);
      __builtin_amdgcn_s_setprio(0);
    }
    if (t + 1 < nt) WAITVM(0);           // own tile-(t+1) loads done before barrier
  }

  // epilogue: lane holds O[q=q_g][d=16jt+4lq+r]; l = lacc[0]
  const float inv = 1.f / lacc[0];
  unsigned short* orow = ob + ((size_t)(bidx * TT + q_g)) * TC + h * TD;
#pragma unroll
  for (int jt = 0; jt < 4; ++jt) {
    unsigned long long pk = 0ull;
#pragma unroll
    for (int r = 0; r < 4; ++r)
      pk |= (unsigned long long)f2bf(oacc[jt][r] * inv) << (16 * r);
    *(unsigned long long*)(orow + jt * 16 + lq * 4) = pk;
  }
}

extern "C" void kernel_launch(void* const* d_in, const int* in_sizes, int n_in,
                              void* d_out, int out_size, void* d_ws, size_t ws_size,
                              hipStream_t stream) {
  const float* Q  = (const float*)d_in[0];
  const float* K  = (const float*)d_in[1];
  const float* V  = (const float*)d_in[2];
  const float* Wq = (const float*)d_in[3];
  const float* bq = (const float*)d_in[4];
  const float* Wk = (const float*)d_in[5];
  const float* bk = (const float*)d_in[6];
  const float* Wv = (const float*)d_in[7];
  const float* bv = (const float*)d_in[8];
  const float* Wo = (const float*)d_in[9];
  const float* bo = (const float*)d_in[10];
  float* out = (float*)d_out;

  char* ws = (char*)d_ws;
  const size_t MB = 1ull << 20;
  unsigned short* WqT = (unsigned short*)(ws + 0 * MB);
  unsigned short* WkT = (unsigned short*)(ws + 2 * MB);
  unsigned short* WvT = (unsigned short*)(ws + 4 * MB);
  unsigned short* WoT = (unsigned short*)(ws + 6 * MB);

  const bool fat = ws_size >= 56 * MB;
  unsigned short *qc, *kc, *vc, *qbuf, *kbuf, *vtbuf, *aout;
  if (fat) {
    qc    = (unsigned short*)(ws + 8 * MB);
    kc    = (unsigned short*)(ws + 16 * MB);
    vc    = (unsigned short*)(ws + 24 * MB);
    qbuf  = (unsigned short*)(ws + 32 * MB);
    kbuf  = (unsigned short*)(ws + 40 * MB);
    vtbuf = (unsigned short*)(ws + 48 * MB);
    aout  = qc;  // qc dead after qkv gemm
  } else {
    qc = kc = vc = (unsigned short*)(ws + 8 * MB);
    qbuf  = (unsigned short*)(ws + 16 * MB);
    kbuf  = (unsigned short*)(ws + 24 * MB);
    vtbuf = (unsigned short*)(ws + 32 * MB);
    aout  = qc;
  }

  dim3 blk(256);
  if (fat) {
    prep_kernel<<<dim3(32, 32, 7), blk, 0, stream>>>(
        Wq, Wk, Wv, Wo, WqT, WkT, WvT, WoT, Q, K, V, qc, kc, vc);
    qkv_gemm_kernel<<<dim3(16, 32, 3), blk, 0, stream>>>(
        qc, kc, vc, WqT, WkT, WvT, bq, bk, bv, qbuf, kbuf, vtbuf, 0);
  } else {
    const int castGrid = MROWS * TC / (256 * 8);  // 2048
    wtrans4_kernel<<<dim3(32, 32, 4), blk, 0, stream>>>(Wq, Wk, Wv, Wo, WqT, WkT, WvT, WoT);
    cast3_kernel<<<dim3(castGrid, 1), blk, 0, stream>>>(Q, Q, Q, qc, qc, qc);
    qkv_gemm_kernel<<<dim3(16, 32, 1), blk, 0, stream>>>(
        qc, qc, qc, WqT, WkT, WvT, bq, bk, bv, qbuf, kbuf, vtbuf, 0);
    cast3_kernel<<<dim3(castGrid, 1), blk, 0, stream>>>(K, K, K, kc, kc, kc);
    qkv_gemm_kernel<<<dim3(16, 32, 1), blk, 0, stream>>>(
        kc, kc, kc, WqT, WkT, WvT, bq, bk, bv, qbuf, kbuf, vtbuf, 1);
    cast3_kernel<<<dim3(castGrid, 1), blk, 0, stream>>>(V, V, V, vc, vc, vc);
    qkv_gemm_kernel<<<dim3(16, 32, 1), blk, 0, stream>>>(
        vc, vc, vc, WqT, WkT, WvT, bq, bk, bv, qbuf, kbuf, vtbuf, 2);
  }

  attn_kernel<<<dim3(1024), blk, 0, stream>>>(qbuf, kbuf, vtbuf, aout);

  oproj_gemm_kernel<<<dim3(16, 64), blk, 0, stream>>>(aout, WoT, bo, out);
}